// Round 3
// baseline (1077.621 us; speedup 1.0000x reference)
//
#include <hip/hip_runtime.h>

// Problem constants (B, L, H, D) = (4, 4096, 8, 64), FACTOR=5
// Inputs/outputs are float32 per the reference (jnp.float32).
#define NB 4
#define LSEQ 4096
#define NH 8
#define ND 64
#define NSAMP 45   // sample_k = min(5*ceil(ln 4096), 4096) = 45
#define NTOP 45    // n_top   = 45

// ---------------------------------------------------------------------------
// Kernel 1: M[b,h,l] = max_s(q.k_s) - sum_s(q.k_s)/LSEQ over 45 sampled keys.
// One wave (64 lanes) per (b,l,h); lane = d. fp32 accumulation.
// M is stored (fp32) in the first 512 KB of d_out — consumed by topk_kernel
// before the cumsum pass overwrites d_out.
// ---------------------------------------------------------------------------
__global__ __launch_bounds__(256) void compute_M_kernel(
        const float* __restrict__ Q,
        const float* __restrict__ K,
        const int* __restrict__ idxS,
        float* __restrict__ Mout) {
    int w = blockIdx.x * 4 + (threadIdx.x >> 6);   // w = ((b*LSEQ + l)*NH + h)
    int lane = threadIdx.x & 63;
    int h = w & (NH - 1);
    int bl = w >> 3;
    int l = bl & (LSEQ - 1);
    int b = bl >> 12;

    float q = Q[(size_t)w * ND + lane];
    const int* is = idxS + (size_t)l * NSAMP;

    float maxv = -INFINITY;
    float sumv = 0.0f;
    for (int s = 0; s < NSAMP; ++s) {
        int idx = is[s];
        float k = K[(((size_t)b * LSEQ + idx) * NH + h) * ND + lane];
        float p = q * k;
        #pragma unroll
        for (int off = 32; off; off >>= 1) p += __shfl_xor(p, off, 64);
        maxv = fmaxf(maxv, p);
        sumv += p;
    }
    if (lane == 0)
        Mout[((size_t)b * NH + h) * LSEQ + l] = maxv - sumv * (1.0f / (float)LSEQ);
}

// ---------------------------------------------------------------------------
// Kernel 2: top-45 indices of M per (b,h). One block per (b,h).
// Iterative argmax with lowest-index tie-break (matches lax.top_k).
// ---------------------------------------------------------------------------
__global__ __launch_bounds__(256) void topk_kernel(
        const float* __restrict__ M, int* __restrict__ Mtop) {
    int bh = blockIdx.x;
    __shared__ float vals[LSEQ];
    __shared__ float redV[256];
    __shared__ int   redI[256];
    const float* m = M + (size_t)bh * LSEQ;
    for (int i = threadIdx.x; i < LSEQ; i += 256) vals[i] = m[i];
    __syncthreads();

    for (int t = 0; t < NTOP; ++t) {
        float bv = -INFINITY; int bi = LSEQ - 1;   // always a valid LDS index
        for (int i = threadIdx.x; i < LSEQ; i += 256) {
            float v = vals[i];
            if (v > bv) { bv = v; bi = i; }   // ascending scan => lowest idx on ties
        }
        redV[threadIdx.x] = bv; redI[threadIdx.x] = bi;
        __syncthreads();
        for (int sft = 128; sft; sft >>= 1) {
            if (threadIdx.x < sft) {
                float ov = redV[threadIdx.x + sft]; int oi = redI[threadIdx.x + sft];
                if (ov > redV[threadIdx.x] ||
                    (ov == redV[threadIdx.x] && oi < redI[threadIdx.x])) {
                    redV[threadIdx.x] = ov; redI[threadIdx.x] = oi;
                }
            }
            __syncthreads();
        }
        if (threadIdx.x == 0) {
            Mtop[bh * NTOP + t] = redI[0];
            vals[redI[0]] = -INFINITY;
        }
        __syncthreads();
    }
}

// ---------------------------------------------------------------------------
// Kernel 3: cumsum of V along L -> out (B,H,L,D) fp32.
// One block (1024 thr) per (b,h): c = tid>>6 in [0,16) chunks of 256 rows,
// d = tid&63. Two-pass block-local scan — no global scratch.
// ---------------------------------------------------------------------------
__global__ __launch_bounds__(1024) void cumsum_kernel(
        const float* __restrict__ V, float* __restrict__ out) {
    const int CH = LSEQ / 16;   // 256
    int bh = blockIdx.x;
    int h = bh & (NH - 1);
    int b = bh >> 3;
    int t = threadIdx.x;
    int c = t >> 6;
    int d = t & 63;

    size_t inbase = (((size_t)b * LSEQ + (size_t)c * CH) * NH + h) * ND + d;
    const size_t stride_in = (size_t)NH * ND;   // 512

    // pass 1: chunk sums
    float s = 0.0f;
    for (int l = 0; l < CH; ++l)
        s += V[inbase + (size_t)l * stride_in];

    __shared__ float part[16][ND];
    part[c][d] = s;
    __syncthreads();

    float run = 0.0f;
    for (int cc = 0; cc < c; ++cc) run += part[cc][d];

    // pass 2: rescan and write
    size_t outbase = ((size_t)bh * LSEQ + (size_t)c * CH) * ND + d;
    for (int l = 0; l < CH; ++l) {
        run += V[inbase + (size_t)l * stride_in];
        out[outbase + (size_t)l * ND] = run;
    }
}

// ---------------------------------------------------------------------------
// Kernel 4: for each selected query u per (b,h): causal softmax over keys
// j <= pos, then attn @ V, written into out at row pos (after cumsum).
// One block (256 thr) per (b,h,u).
// ---------------------------------------------------------------------------
__global__ __launch_bounds__(256) void attn_rows_kernel(
        const float* __restrict__ Q,
        const float* __restrict__ K,
        const float* __restrict__ V,
        const int* __restrict__ Mtop,
        float* __restrict__ out) {
    int u  = blockIdx.x % NTOP;
    int bh = blockIdx.x / NTOP;
    int h = bh & (NH - 1);
    int b = bh >> 3;
    int pos = Mtop[bh * NTOP + u];
    int n = pos + 1;
    int tid = threadIdx.x;

    __shared__ float qs[ND];
    __shared__ float sc[LSEQ];
    __shared__ float red[256];

    if (tid < ND)
        qs[tid] = Q[(((size_t)b * LSEQ + pos) * NH + h) * ND + tid];
    __syncthreads();

    // Pass 1: scores for j in [0, pos]
    float lmax = -INFINITY;
    for (int j = tid; j < n; j += 256) {
        const float4* kr = reinterpret_cast<const float4*>(
            K + (((size_t)b * LSEQ + j) * NH + h) * ND);
        float s = 0.0f;
        #pragma unroll
        for (int c4 = 0; c4 < 16; ++c4) {
            float4 kv = kr[c4];
            int base = c4 * 4;
            s += qs[base + 0] * kv.x + qs[base + 1] * kv.y
               + qs[base + 2] * kv.z + qs[base + 3] * kv.w;
        }
        s *= 0.125f;   // 1/sqrt(64)
        sc[j] = s;
        lmax = fmaxf(lmax, s);
    }
    red[tid] = lmax; __syncthreads();
    for (int sft = 128; sft; sft >>= 1) {
        if (tid < sft) red[tid] = fmaxf(red[tid], red[tid + sft]);
        __syncthreads();
    }
    float m = red[0];
    __syncthreads();

    // Pass 2: exp and sum
    float lsum = 0.0f;
    for (int j = tid; j < n; j += 256) {
        float p = __expf(sc[j] - m);
        sc[j] = p;
        lsum += p;
    }
    red[tid] = lsum; __syncthreads();
    for (int sft = 128; sft; sft >>= 1) {
        if (tid < sft) red[tid] += red[tid + sft];
        __syncthreads();
    }
    float denom = red[0];
    __syncthreads();

    // Pass 3: out[d] = sum_j p_j * V[j,d] / denom
    int d = tid & 63;
    int g = tid >> 6;   // 4 groups
    float acc = 0.0f;
    for (int j = g; j < n; j += 4)
        acc += sc[j] * V[(((size_t)b * LSEQ + j) * NH + h) * ND + d];
    red[tid] = acc; __syncthreads();
    if (tid < ND) {
        float tot = red[tid] + red[tid + 64] + red[tid + 128] + red[tid + 192];
        out[((size_t)bh * LSEQ + pos) * ND + d] = tot / denom;
    }
}

// ---------------------------------------------------------------------------
extern "C" void kernel_launch(void* const* d_in, const int* in_sizes, int n_in,
                              void* d_out, int out_size, void* d_ws, size_t ws_size,
                              hipStream_t stream) {
    const float* Q = (const float*)d_in[0];
    const float* K = (const float*)d_in[1];
    const float* V = (const float*)d_in[2];
    const int* idxS = (const int*)d_in[3];
    float* out = (float*)d_out;

    // M (fp32, 512 KB) lives in d_out — consumed by topk before cumsum
    // overwrites d_out. Only Mtop (5760 B) uses the workspace.
    float* Mbuf = (float*)d_out;
    int*   Mtop = (int*)d_ws;

    // 1) M scores: one wave per (b,l,h)
    compute_M_kernel<<<NB * LSEQ * NH / 4, 256, 0, stream>>>(Q, K, idxS, Mbuf);

    // 2) top-45 per (b,h)
    topk_kernel<<<NB * NH, 256, 0, stream>>>(Mbuf, Mtop);

    // 3) cumsum of V along L -> out (overwrites the M region)
    cumsum_kernel<<<NB * NH, 1024, 0, stream>>>(V, out);

    // 4) attention rows overwrite their positions
    attn_rows_kernel<<<NB * NH * NTOP, 256, 0, stream>>>(Q, K, V, Mtop, out);
}